// Round 19
// baseline (436.751 us; speedup 1.0000x reference)
//
#include <hip/hip_runtime.h>
#include <hip/hip_bf16.h>
#include <math.h>

#define N_BATCH 128
#define C_CH    512
#define HF      38
#define WF      38
#define K1      25088   // 512*49
#define NH      4096
#define NCLS    21
#define NBOX    80
#define STEPS1  784     // K1/32
#define STEPS2  128     // NH/32

typedef __attribute__((ext_vector_type(8))) short s16x8;
typedef __attribute__((ext_vector_type(4))) float f32x4;

__device__ __forceinline__ unsigned short bf_rne(float x) {
  unsigned u = __float_as_uint(x);
  return (unsigned short)((u + 0x7FFFu + ((u >> 16) & 1u)) >> 16);
}

__device__ __forceinline__ void gload16(const void* g, void* l) {
  __builtin_amdgcn_global_load_lds(
      (const __attribute__((address_space(1))) unsigned int*)g,
      (__attribute__((address_space(3))) unsigned int*)l, 16, 0, 0);
}

// ---------------------------------------------------------------------------
// Kernel 1: ROI crop + adaptive 7x7 maxpool -> 1 bf16 plane (group-major
// fragment order): group g = S*8 + mt; short addr = g*512 + (kg*16+mlo)*8 + e
// ---------------------------------------------------------------------------
__global__ __launch_bounds__(256) void pool_kernel(
    const float* __restrict__ x, const int* __restrict__ rp,
    unsigned short* __restrict__ Asw) {
  const int n = blockIdx.y, cb = blockIdx.x, tid = threadIdx.x;
  const int r = rp[n*4+0], c = rp[n*4+1], w = rp[n*4+2], h = rp[n*4+3];
  __shared__ float tile[8][24][25];
  __shared__ float pout[392];
  const int ch = tid >> 5, l32 = tid & 31;
  const float* xc = x + (((size_t)(n*C_CH + cb*8 + ch))*HF + c)*WF + r;
  for (int y = 0; y < h; ++y)
    for (int xx = l32; xx < w; xx += 32)
      tile[ch][y][xx] = xc[y*WF + xx];
  __syncthreads();
  for (int o = tid; o < 8*49; o += 256) {
    int ch2 = o / 49, ij = o - ch2*49, i = ij / 7, j = ij - i*7;
    int rs = (i*h)/7, re = ((i+1)*h + 6)/7;
    int cs = (j*w)/7, ce = ((j+1)*w + 6)/7;
    float m = -INFINITY;
    for (int y = rs; y < re; ++y)
      for (int xx = cs; xx < ce; ++xx)
        m = fmaxf(m, tile[ch2][y][xx]);
    pout[o] = m;
  }
  __syncthreads();
  if (tid < 49) {
    const int mt = n >> 4, mlo = n & 15;
    const int kl0 = tid * 8;
    const int kg0 = cb*392 + kl0;           // 8-aligned, one (S,kg) group
    const int S = kg0 >> 5, kg = (kg0 >> 3) & 3;
    size_t base = ((size_t)S*8 + mt)*512 + (size_t)(kg*16 + mlo)*8;
    unsigned short q[8];
    #pragma unroll
    for (int e = 0; e < 8; ++e) q[e] = bf_rne(pout[kl0 + e]);
    ushort4 lo; lo.x=q[0]; lo.y=q[1]; lo.z=q[2]; lo.w=q[3];
    ushort4 hi; hi.x=q[4]; hi.y=q[5]; hi.z=q[6]; hi.w=q[7];
    *(ushort4*)(Asw + base)     = lo;
    *(ushort4*)(Asw + base + 4) = hi;
  }
}

// ---------------------------------------------------------------------------
// Kernel 2: m97-style barrier'd split-K MFMA GEMM (round-17 structure,
// the session best) + runtime `reps` loop: the whole body (acc init,
// staging from step 0, K-loop, output write) runs `reps` times inside ONE
// dispatch. reps=2 for GEMM1 makes the dispatch outlast the harness's
// poison fills so its counters appear in top-5. Output is written every
// rep with identical values -> bit-identical result, nothing DCE-able.
// ---------------------------------------------------------------------------
__global__ __launch_bounds__(256, 3) void gemm_v14r(
    const unsigned short* __restrict__ Asw, const float* __restrict__ B,
    float* __restrict__ part, const int nsteps, const int reps) {
  __shared__ char smem[49152];          // [2][A:8KB | B:16KB]
  const int tid = threadIdx.x, lane = tid & 63, wv = tid >> 6;
  const int wr = wv >> 1, wc = wv & 1;
  const int nb = blockIdx.x, ks = blockIdx.y;
  const int l15 = lane & 15, lq = lane >> 4;
  const float* Bg0 = B + (size_t)nb * 128;

#define STAGE(s, bufb) do { \
    char* Ad = smem + (bufb); \
    char* Bd = smem + (bufb) + 8192; \
    _Pragma("unroll") \
    for (int t_ = 0; t_ < 6; ++t_) { \
      const int i_ = wv*6 + t_; \
      if (i_ < 8) { \
        gload16((const char*)Asw + (((size_t)(ks*nsteps + (s))*8 + i_) << 10) \
                    + lane*16, \
                Ad + (i_ << 10)); \
      } else { \
        const int j_ = i_ - 8; \
        const int row_ = 2*j_ + (lane >> 5); \
        const int gc_ = ((lane & 31)*4) ^ (8*((row_ >> 3) & 3)); \
        gload16(Bg0 + ((size_t)(ks*nsteps + (s))*32 + row_)*NH + gc_, \
                Bd + (j_ << 10)); \
      } \
    } } while (0)

  for (int rep = 0; rep < reps; ++rep) {
    f32x4 acc[4][4];
    #pragma unroll
    for (int i = 0; i < 4; ++i)
      #pragma unroll
      for (int j = 0; j < 4; ++j) acc[i][j] = (f32x4){0.f, 0.f, 0.f, 0.f};

    STAGE(0, 0);
    __syncthreads();

    int bufb = 0;
    for (int s = 0; s < nsteps; ++s) {
      if (s + 1 < nsteps) STAGE(s + 1, bufb ^ 24576);  // issue before compute
      const char* Ab = smem + bufb;
      const float* Bf = (const float*)(smem + bufb + 8192);
      s16x8 bf0[4];
      #pragma unroll
      for (int nt = 0; nt < 4; ++nt) {
        #pragma unroll
        for (int e = 0; e < 8; ++e) {
          float xv = Bf[(lq*8 + e)*128 + ((wc*64 + nt*16 + l15) ^ (8*lq))];
          bf0[nt][e] = (short)bf_rne(xv);
        }
      }
      #pragma unroll
      for (int ml = 0; ml < 4; ++ml) {
        const s16x8 a0 = *(const s16x8*)(Ab + ((wr*4 + ml) << 10) + lane*16);
        #pragma unroll
        for (int nt = 0; nt < 4; ++nt)
          acc[ml][nt] = __builtin_amdgcn_mfma_f32_16x16x32_bf16(
              a0, bf0[nt], acc[ml][nt], 0, 0, 0);
      }
      __syncthreads();
      bufb ^= 24576;
    }
    // epilogue each rep (identical values -> idempotent)
    float* Pb = part + (size_t)ks*N_BATCH*NH + (size_t)nb*128 + wc*64;
    #pragma unroll
    for (int ml = 0; ml < 4; ++ml)
      #pragma unroll
      for (int nt = 0; nt < 4; ++nt)
        #pragma unroll
        for (int rr = 0; rr < 4; ++rr)
          Pb[(size_t)((wr*4 + ml)*16 + lq*4 + rr)*NH + nt*16 + l15]
              = acc[ml][nt][rr];
    __syncthreads();    // LDS quiesced before next rep restages buffer 0
  }
#undef STAGE
}

// ---------------------------------------------------------------------------
// Kernel 3: reduce split-K partials + bias + relu.
// mode 0: emit group-major 1-plane bf16 (A of next GEMM). mode 1: fp32 rows.
// ---------------------------------------------------------------------------
__global__ __launch_bounds__(256) void reduce_k(
    const float* __restrict__ part, const float* __restrict__ bias,
    unsigned short* __restrict__ AswOut, float* __restrict__ f32out,
    int KS, int mode) {
  const int idx = blockIdx.x*256 + threadIdx.x;     // float4 idx, 131072 total
  float4 s = ((const float4*)part)[idx];
  for (int k2 = 1; k2 < KS; ++k2) {
    float4 p = ((const float4*)part)[(size_t)k2*131072 + idx];
    s.x += p.x; s.y += p.y; s.z += p.z; s.w += p.w;
  }
  float4 bv = ((const float4*)bias)[idx & 1023];
  float v[4];
  v[0] = fmaxf(s.x + bv.x, 0.f); v[1] = fmaxf(s.y + bv.y, 0.f);
  v[2] = fmaxf(s.z + bv.z, 0.f); v[3] = fmaxf(s.w + bv.w, 0.f);
  if (mode == 1) {
    float4 o; o.x = v[0]; o.y = v[1]; o.z = v[2]; o.w = v[3];
    ((float4*)f32out)[idx] = o;
  } else {
    int m = idx >> 10, k = (idx & 1023) * 4;
    int S = k >> 5, kg = (k >> 3) & 3, e0 = k & 7;
    size_t base = ((size_t)S*8 + (m >> 4))*512
                + (size_t)(kg*16 + (m & 15))*8 + e0;
    ushort4 st;
    st.x = bf_rne(v[0]); st.y = bf_rne(v[1]);
    st.z = bf_rne(v[2]); st.w = bf_rne(v[3]);
    *(ushort4*)(AswOut + base) = st;
  }
}

// ---------------------------------------------------------------------------
// Kernel 4a: transpose Wcls|Wbox into WT[101][4096]
// ---------------------------------------------------------------------------
__global__ __launch_bounds__(256) void head_transpose(
    const float* __restrict__ Wcls, const float* __restrict__ Wbox,
    float* __restrict__ WT) {
  const int c = blockIdx.x;
  const float* src; int stride;
  if (c < NCLS) { src = Wcls + c; stride = NCLS; }
  else          { src = Wbox + (c - NCLS); stride = NBOX; }
  for (int k = threadIdx.x; k < NH; k += 256)
    WT[(size_t)c*NH + k] = src[(size_t)k*stride];
}

// ---------------------------------------------------------------------------
// Kernel 4b: fused head — dots (8 waves x stride-8 cols, h2 row in LDS)
// + softmax(21) + bbox(80).
// ---------------------------------------------------------------------------
__global__ __launch_bounds__(512) void head_fused(
    const float* __restrict__ h2, const float* __restrict__ WT,
    const int* __restrict__ rp, float* __restrict__ out) {
  const int n = blockIdx.x, tid = threadIdx.x;
  const int wv = tid >> 6, lane = tid & 63;
  __shared__ float h2s[NH];
  __shared__ float dots[104];
  __shared__ float red[2];
  for (int i = tid; i < NH/4; i += 512)
    ((float4*)h2s)[i] = ((const float4*)(h2 + (size_t)n*NH))[i];
  __syncthreads();
  for (int c = wv; c < NCLS + NBOX; c += 8) {
    const float4* hp = (const float4*)h2s;
    const float4* wp = (const float4*)(WT + (size_t)c*NH);
    float s0=0.f, s1=0.f, s2=0.f, s3=0.f;
    #pragma unroll
    for (int it = 0; it < 16; ++it) {
      float4 a = hp[it*64 + lane];
      float4 b = wp[it*64 + lane];
      s0 = fmaf(a.x, b.x, s0); s1 = fmaf(a.y, b.y, s1);
      s2 = fmaf(a.z, b.z, s2); s3 = fmaf(a.w, b.w, s3);
    }
    float v = (s0 + s1) + (s2 + s3);
    #pragma unroll
    for (int m = 32; m >= 1; m >>= 1) v += __shfl_xor(v, m, 64);
    if (lane == 0) dots[c] = v;
  }
  __syncthreads();
  if (tid == 0) {
    float m = dots[0];
    for (int i = 1; i < NCLS; ++i) m = fmaxf(m, dots[i]);
    float s = 0.f;
    for (int i = 0; i < NCLS; ++i) s += expf(dots[i] - m);
    red[0] = m; red[1] = s;
  }
  __syncthreads();
  if (tid < NCLS) {
    out[(size_t)n*NCLS + tid] = expf(dots[tid] - red[0]) / red[1];
  } else if (tid < NCLS + NBOX) {
    const int j = tid - NCLS;
    const float t  = dots[tid];
    const float rf = (float)rp[n*4+0];
    const float cf = (float)rp[n*4+1];
    const float wf = (float)rp[n*4+2];
    const float hf = (float)rp[n*4+3];
    float p;
    switch (j & 3) {
      case 0:  p = ceilf (__fmul_rn(__fadd_rn(__fmul_rn(wf, t), rf), 16.f)) - 1.f; break;
      case 1:  p = ceilf (__fmul_rn(__fadd_rn(__fmul_rn(hf, t), cf), 16.f)) - 1.f; break;
      case 2:  p = floorf(__fmul_rn(__fmul_rn(wf, expf(t)), 16.f)) + 1.f; break;
      default: p = floorf(__fmul_rn(__fmul_rn(hf, expf(t)), 16.f)) + 1.f; break;
    }
    out[(size_t)N_BATCH*NCLS + (size_t)n*NBOX + j] = p;
  }
}

// ---------------------------------------------------------------------------
extern "C" void kernel_launch(void* const* d_in, const int* in_sizes, int n_in,
                              void* d_out, int out_size, void* d_ws, size_t ws_size,
                              hipStream_t stream) {
  const float* x    = (const float*)d_in[0];
  const int*   rp   = (const int*)  d_in[1];
  const float* W1   = (const float*)d_in[2];
  const float* b1   = (const float*)d_in[3];
  const float* W2   = (const float*)d_in[4];
  const float* b2   = (const float*)d_in[5];
  const float* Wcls = (const float*)d_in[6];
  const float* Wbox = (const float*)d_in[7];
  float* out = (float*)d_out;

  // ws: Asw1 (6.4MB) | Asw2 (1.05MB) | h2f | WT | part (~42 MB total)
  char* wp = (char*)d_ws;
  unsigned short* Asw1 = (unsigned short*)wp; wp += (size_t)STEPS1*8192;
  unsigned short* Asw2 = (unsigned short*)wp; wp += (size_t)STEPS2*8192;
  float* h2f = (float*)wp;            wp += (size_t)N_BATCH*NH*4;
  float* WT  = (float*)wp;            wp += (size_t)(NCLS+NBOX)*NH*4;
  float* part = (float*)wp;
  const size_t fixed = (size_t)(wp - (char*)d_ws);
  const size_t slab = (size_t)N_BATCH*NH*4;       // 2 MB per partial
  int KS1 = 16, KS2 = 16;
  if (fixed + 16*slab > ws_size) { KS1 = 8; KS2 = 8; }

  pool_kernel<<<dim3(64, 128), 256, 0, stream>>>(x, rp, Asw1);
  head_transpose<<<dim3(NCLS + NBOX), 256, 0, stream>>>(Wcls, Wbox, WT);

  // GEMM1: round-17 structure, reps=2 ATTRIBUTION PROBE — one ~290us
  // dispatch so G1's counters appear in rocprof top-5 above the fills.
  gemm_v14r<<<dim3(32, KS1), 256, 0, stream>>>(Asw1, W1, part, STEPS1/KS1, 2);
  reduce_k<<<dim3(512), 256, 0, stream>>>(part, b1, Asw2, nullptr, KS1, 0);

  // GEMM2: reps=1 (normal).
  gemm_v14r<<<dim3(32, KS2), 256, 0, stream>>>(Asw2, W2, part, STEPS2/KS2, 1);
  reduce_k<<<dim3(512), 256, 0, stream>>>(part, b2, nullptr, h2f, KS2, 1);

  head_fused<<<dim3(128), 512, 0, stream>>>(h2f, WT, rp, out);
}

// Round 20
// 256.627 us; speedup vs baseline: 1.7019x; 1.7019x over previous
//
#include <hip/hip_runtime.h>
#include <hip/hip_bf16.h>
#include <math.h>

#define N_BATCH 128
#define C_CH    512
#define HF      38
#define WF      38
#define K1      25088   // 512*49
#define NH      4096
#define NCLS    21
#define NBOX    80
#define STEPS1  784     // K1/32
#define STEPS2  128     // NH/32

typedef __attribute__((ext_vector_type(8))) short s16x8;
typedef __attribute__((ext_vector_type(4))) float f32x4;

__device__ __forceinline__ unsigned short bf_rne(float x) {
  unsigned u = __float_as_uint(x);
  return (unsigned short)((u + 0x7FFFu + ((u >> 16) & 1u)) >> 16);
}

__device__ __forceinline__ void gload16(const void* g, void* l) {
  __builtin_amdgcn_global_load_lds(
      (const __attribute__((address_space(1))) unsigned int*)g,
      (__attribute__((address_space(3))) unsigned int*)l, 16, 0, 0);
}

// ---------------------------------------------------------------------------
// Kernel 1: ROI crop + adaptive 7x7 maxpool -> 1 bf16 plane (group-major
// fragment order): group g = S*8 + mt; short addr = g*512 + (kg*16+mlo)*8 + e
// ---------------------------------------------------------------------------
__global__ __launch_bounds__(256) void pool_kernel(
    const float* __restrict__ x, const int* __restrict__ rp,
    unsigned short* __restrict__ Asw) {
  const int n = blockIdx.y, cb = blockIdx.x, tid = threadIdx.x;
  const int r = rp[n*4+0], c = rp[n*4+1], w = rp[n*4+2], h = rp[n*4+3];
  __shared__ float tile[8][24][25];
  __shared__ float pout[392];
  const int ch = tid >> 5, l32 = tid & 31;
  const float* xc = x + (((size_t)(n*C_CH + cb*8 + ch))*HF + c)*WF + r;
  for (int y = 0; y < h; ++y)
    for (int xx = l32; xx < w; xx += 32)
      tile[ch][y][xx] = xc[y*WF + xx];
  __syncthreads();
  for (int o = tid; o < 8*49; o += 256) {
    int ch2 = o / 49, ij = o - ch2*49, i = ij / 7, j = ij - i*7;
    int rs = (i*h)/7, re = ((i+1)*h + 6)/7;
    int cs = (j*w)/7, ce = ((j+1)*w + 6)/7;
    float m = -INFINITY;
    for (int y = rs; y < re; ++y)
      for (int xx = cs; xx < ce; ++xx)
        m = fmaxf(m, tile[ch2][y][xx]);
    pout[o] = m;
  }
  __syncthreads();
  if (tid < 49) {
    const int mt = n >> 4, mlo = n & 15;
    const int kl0 = tid * 8;
    const int kg0 = cb*392 + kl0;           // 8-aligned, one (S,kg) group
    const int S = kg0 >> 5, kg = (kg0 >> 3) & 3;
    size_t base = ((size_t)S*8 + mt)*512 + (size_t)(kg*16 + mlo)*8;
    unsigned short q[8];
    #pragma unroll
    for (int e = 0; e < 8; ++e) q[e] = bf_rne(pout[kl0 + e]);
    ushort4 lo; lo.x=q[0]; lo.y=q[1]; lo.z=q[2]; lo.w=q[3];
    ushort4 hi; hi.x=q[4]; hi.y=q[5]; hi.z=q[6]; hi.w=q[7];
    *(ushort4*)(Asw + base)     = lo;
    *(ushort4*)(Asw + base + 4) = hi;
  }
}

// ---------------------------------------------------------------------------
// Kernel 2: m97-style barrier'd split-K MFMA GEMM, BN=64 for 4 blocks/CU.
// BM=128, BN=64, BK=32, 4 waves (wr=wv>>1, wc=wv&1): wave = 4mt x 2nt.
// LDS/buffer = A 8KB + B 8KB; double-buffered = 32KB -> 4 blocks/CU; grid
// (64,16)=1024 blocks = exactly 4.0/CU (no tail). 4 independent barrier
// groups per CU keep ~64KB reads in flight (vs 2x24KB sawtooth at BN=128,
// which measured 2.5 TB/s / 21.6% occupancy in the round-19 probe).
// Staging: 16 gload16/step, 4/wave (waves 0-1: A groups, waves 2-3: B rows).
// B source cols XOR-pre-swizzled so fragment reads are 2-way banked (free).
// Arithmetic identical to rounds 14-19 (absmax must stay 2.0).
// ---------------------------------------------------------------------------
__global__ __launch_bounds__(256, 4) void gemm_v16(
    const unsigned short* __restrict__ Asw, const float* __restrict__ B,
    float* __restrict__ part, const int nsteps) {
  __shared__ char smem[32768];          // [2][A:8KB | B:8KB]
  const int tid = threadIdx.x, lane = tid & 63, wv = tid >> 6;
  const int wr = wv >> 1, wc = wv & 1;
  const int nb = blockIdx.x, ks = blockIdx.y;
  const int l15 = lane & 15, lq = lane >> 4;
  const float* Bg0 = B + (size_t)nb * 64;

  f32x4 acc[4][2];
  #pragma unroll
  for (int i = 0; i < 4; ++i)
    #pragma unroll
    for (int j = 0; j < 2; ++j) acc[i][j] = (f32x4){0.f, 0.f, 0.f, 0.f};

  // ops 0..7 = A groups (1KB each); ops 8..15 = B 4-row chunks (1KB each:
  // op j_ covers rows 4j_..4j_+3, each row 256B; lane: row 4j_+(lane>>4),
  // LDS col (lane&15)*4, source col XOR-swizzled by 8*((j_>>1)&3)).
#define STAGE(s, bufb) do { \
    char* Ad = smem + (bufb); \
    char* Bd = smem + (bufb) + 8192; \
    _Pragma("unroll") \
    for (int t_ = 0; t_ < 4; ++t_) { \
      const int i_ = wv*4 + t_; \
      if (i_ < 8) { \
        gload16((const char*)Asw + (((size_t)(ks*nsteps + (s))*8 + i_) << 10) \
                    + lane*16, \
                Ad + (i_ << 10)); \
      } else { \
        const int j_ = i_ - 8; \
        const int row_ = 4*j_ + (lane >> 4); \
        const int gc_ = ((lane & 15)*4) ^ (8*((j_ >> 1) & 3)); \
        gload16(Bg0 + ((size_t)(ks*nsteps + (s))*32 + row_)*NH + gc_, \
                Bd + (j_ << 10)); \
      } \
    } } while (0)

  STAGE(0, 0);
  __syncthreads();

  int bufb = 0;
  for (int s = 0; s < nsteps; ++s) {
    if (s + 1 < nsteps) STAGE(s + 1, bufb ^ 16384);  // issue before compute
    const char* Ab = smem + bufb;
    const float* Bf = (const float*)(smem + bufb + 8192);
    // B fragments: global col W = wc*32 + nt*16 + l15 at row lq*8+e is
    // stored at LDS col W ^ (8*lq); 64-float row stride -> 2-way banks.
    s16x8 bf0[2];
    #pragma unroll
    for (int nt = 0; nt < 2; ++nt) {
      #pragma unroll
      for (int e = 0; e < 8; ++e) {
        float xv = Bf[(lq*8 + e)*64 + ((wc*32 + nt*16 + l15) ^ (8*lq))];
        bf0[nt][e] = (short)bf_rne(xv);
      }
    }
    #pragma unroll
    for (int ml = 0; ml < 4; ++ml) {
      const s16x8 a0 = *(const s16x8*)(Ab + ((wr*4 + ml) << 10) + lane*16);
      #pragma unroll
      for (int nt = 0; nt < 2; ++nt)
        acc[ml][nt] = __builtin_amdgcn_mfma_f32_16x16x32_bf16(
            a0, bf0[nt], acc[ml][nt], 0, 0, 0);
    }
    __syncthreads();
    bufb ^= 16384;
  }
#undef STAGE
  // epilogue: C/D layout row=(lane>>4)*4+rr, col=lane&15
  float* Pb = part + (size_t)ks*N_BATCH*NH + (size_t)nb*64 + wc*32;
  #pragma unroll
  for (int ml = 0; ml < 4; ++ml)
    #pragma unroll
    for (int nt = 0; nt < 2; ++nt)
      #pragma unroll
      for (int rr = 0; rr < 4; ++rr)
        Pb[(size_t)((wr*4 + ml)*16 + lq*4 + rr)*NH + nt*16 + l15]
            = acc[ml][nt][rr];
}

// ---------------------------------------------------------------------------
// Kernel 3: reduce split-K partials + bias + relu.
// mode 0: emit group-major 1-plane bf16 (A of next GEMM). mode 1: fp32 rows.
// ---------------------------------------------------------------------------
__global__ __launch_bounds__(256) void reduce_k(
    const float* __restrict__ part, const float* __restrict__ bias,
    unsigned short* __restrict__ AswOut, float* __restrict__ f32out,
    int KS, int mode) {
  const int idx = blockIdx.x*256 + threadIdx.x;     // float4 idx, 131072 total
  float4 s = ((const float4*)part)[idx];
  for (int k2 = 1; k2 < KS; ++k2) {
    float4 p = ((const float4*)part)[(size_t)k2*131072 + idx];
    s.x += p.x; s.y += p.y; s.z += p.z; s.w += p.w;
  }
  float4 bv = ((const float4*)bias)[idx & 1023];
  float v[4];
  v[0] = fmaxf(s.x + bv.x, 0.f); v[1] = fmaxf(s.y + bv.y, 0.f);
  v[2] = fmaxf(s.z + bv.z, 0.f); v[3] = fmaxf(s.w + bv.w, 0.f);
  if (mode == 1) {
    float4 o; o.x = v[0]; o.y = v[1]; o.z = v[2]; o.w = v[3];
    ((float4*)f32out)[idx] = o;
  } else {
    int m = idx >> 10, k = (idx & 1023) * 4;
    int S = k >> 5, kg = (k >> 3) & 3, e0 = k & 7;
    size_t base = ((size_t)S*8 + (m >> 4))*512
                + (size_t)(kg*16 + (m & 15))*8 + e0;
    ushort4 st;
    st.x = bf_rne(v[0]); st.y = bf_rne(v[1]);
    st.z = bf_rne(v[2]); st.w = bf_rne(v[3]);
    *(ushort4*)(AswOut + base) = st;
  }
}

// ---------------------------------------------------------------------------
// Kernel 4a: transpose Wcls|Wbox into WT[101][4096]
// ---------------------------------------------------------------------------
__global__ __launch_bounds__(256) void head_transpose(
    const float* __restrict__ Wcls, const float* __restrict__ Wbox,
    float* __restrict__ WT) {
  const int c = blockIdx.x;
  const float* src; int stride;
  if (c < NCLS) { src = Wcls + c; stride = NCLS; }
  else          { src = Wbox + (c - NCLS); stride = NBOX; }
  for (int k = threadIdx.x; k < NH; k += 256)
    WT[(size_t)c*NH + k] = src[(size_t)k*stride];
}

// ---------------------------------------------------------------------------
// Kernel 4b: fused head — dots (8 waves x stride-8 cols, h2 row in LDS)
// + softmax(21) + bbox(80).
// ---------------------------------------------------------------------------
__global__ __launch_bounds__(512) void head_fused(
    const float* __restrict__ h2, const float* __restrict__ WT,
    const int* __restrict__ rp, float* __restrict__ out) {
  const int n = blockIdx.x, tid = threadIdx.x;
  const int wv = tid >> 6, lane = tid & 63;
  __shared__ float h2s[NH];
  __shared__ float dots[104];
  __shared__ float red[2];
  for (int i = tid; i < NH/4; i += 512)
    ((float4*)h2s)[i] = ((const float4*)(h2 + (size_t)n*NH))[i];
  __syncthreads();
  for (int c = wv; c < NCLS + NBOX; c += 8) {
    const float4* hp = (const float4*)h2s;
    const float4* wp = (const float4*)(WT + (size_t)c*NH);
    float s0=0.f, s1=0.f, s2=0.f, s3=0.f;
    #pragma unroll
    for (int it = 0; it < 16; ++it) {
      float4 a = hp[it*64 + lane];
      float4 b = wp[it*64 + lane];
      s0 = fmaf(a.x, b.x, s0); s1 = fmaf(a.y, b.y, s1);
      s2 = fmaf(a.z, b.z, s2); s3 = fmaf(a.w, b.w, s3);
    }
    float v = (s0 + s1) + (s2 + s3);
    #pragma unroll
    for (int m = 32; m >= 1; m >>= 1) v += __shfl_xor(v, m, 64);
    if (lane == 0) dots[c] = v;
  }
  __syncthreads();
  if (tid == 0) {
    float m = dots[0];
    for (int i = 1; i < NCLS; ++i) m = fmaxf(m, dots[i]);
    float s = 0.f;
    for (int i = 0; i < NCLS; ++i) s += expf(dots[i] - m);
    red[0] = m; red[1] = s;
  }
  __syncthreads();
  if (tid < NCLS) {
    out[(size_t)n*NCLS + tid] = expf(dots[tid] - red[0]) / red[1];
  } else if (tid < NCLS + NBOX) {
    const int j = tid - NCLS;
    const float t  = dots[tid];
    const float rf = (float)rp[n*4+0];
    const float cf = (float)rp[n*4+1];
    const float wf = (float)rp[n*4+2];
    const float hf = (float)rp[n*4+3];
    float p;
    switch (j & 3) {
      case 0:  p = ceilf (__fmul_rn(__fadd_rn(__fmul_rn(wf, t), rf), 16.f)) - 1.f; break;
      case 1:  p = ceilf (__fmul_rn(__fadd_rn(__fmul_rn(hf, t), cf), 16.f)) - 1.f; break;
      case 2:  p = floorf(__fmul_rn(__fmul_rn(wf, expf(t)), 16.f)) + 1.f; break;
      default: p = floorf(__fmul_rn(__fmul_rn(hf, expf(t)), 16.f)) + 1.f; break;
    }
    out[(size_t)N_BATCH*NCLS + (size_t)n*NBOX + j] = p;
  }
}

// ---------------------------------------------------------------------------
extern "C" void kernel_launch(void* const* d_in, const int* in_sizes, int n_in,
                              void* d_out, int out_size, void* d_ws, size_t ws_size,
                              hipStream_t stream) {
  const float* x    = (const float*)d_in[0];
  const int*   rp   = (const int*)  d_in[1];
  const float* W1   = (const float*)d_in[2];
  const float* b1   = (const float*)d_in[3];
  const float* W2   = (const float*)d_in[4];
  const float* b2   = (const float*)d_in[5];
  const float* Wcls = (const float*)d_in[6];
  const float* Wbox = (const float*)d_in[7];
  float* out = (float*)d_out;

  // ws: Asw1 (6.4MB) | Asw2 (1.05MB) | h2f | WT | part (~42 MB total)
  char* wp = (char*)d_ws;
  unsigned short* Asw1 = (unsigned short*)wp; wp += (size_t)STEPS1*8192;
  unsigned short* Asw2 = (unsigned short*)wp; wp += (size_t)STEPS2*8192;
  float* h2f = (float*)wp;            wp += (size_t)N_BATCH*NH*4;
  float* WT  = (float*)wp;            wp += (size_t)(NCLS+NBOX)*NH*4;
  float* part = (float*)wp;
  const size_t fixed = (size_t)(wp - (char*)d_ws);
  const size_t slab = (size_t)N_BATCH*NH*4;       // 2 MB per partial
  int KS1 = 16, KS2 = 16;
  if (fixed + 16*slab > ws_size) { KS1 = 8; KS2 = 8; }

  pool_kernel<<<dim3(64, 128), 256, 0, stream>>>(x, rp, Asw1);
  head_transpose<<<dim3(NCLS + NBOX), 256, 0, stream>>>(Wcls, Wbox, WT);

  // GEMM1: BN=64, grid (64,16)=1024 blocks = exactly 4/CU, nsteps=49.
  gemm_v16<<<dim3(64, KS1), 256, 0, stream>>>(Asw1, W1, part, STEPS1/KS1);
  reduce_k<<<dim3(512), 256, 0, stream>>>(part, b1, Asw2, nullptr, KS1, 0);

  // GEMM2: BN=64, grid (64,16)=1024 blocks, nsteps=8.
  gemm_v16<<<dim3(64, KS2), 256, 0, stream>>>(Asw2, W2, part, STEPS2/KS2);
  reduce_k<<<dim3(512), 256, 0, stream>>>(part, b2, nullptr, h2f, KS2, 1);

  head_fused<<<dim3(128), 512, 0, stream>>>(h2f, WT, rp, out);
}

// Round 21
// 242.796 us; speedup vs baseline: 1.7988x; 1.0570x over previous
//
#include <hip/hip_runtime.h>
#include <hip/hip_bf16.h>
#include <math.h>

#define N_BATCH 128
#define C_CH    512
#define HF      38
#define WF      38
#define K1      25088   // 512*49
#define NH      4096
#define NCLS    21
#define NBOX    80
#define STEPS1  784     // K1/32
#define STEPS2  128     // NH/32

typedef __attribute__((ext_vector_type(8))) short s16x8;
typedef __attribute__((ext_vector_type(4))) float f32x4;

__device__ __forceinline__ unsigned short bf_rne(float x) {
  unsigned u = __float_as_uint(x);
  return (unsigned short)((u + 0x7FFFu + ((u >> 16) & 1u)) >> 16);
}

__device__ __forceinline__ void gload16(const void* g, void* l) {
  __builtin_amdgcn_global_load_lds(
      (const __attribute__((address_space(1))) unsigned int*)g,
      (__attribute__((address_space(3))) unsigned int*)l, 16, 0, 0);
}

// ---------------------------------------------------------------------------
// Kernel 1: ROI crop + adaptive 7x7 maxpool -> 1 bf16 plane (group-major
// fragment order): group g = S*8 + mt; short addr = g*512 + (kg*16+mlo)*8 + e
// ---------------------------------------------------------------------------
__global__ __launch_bounds__(256) void pool_kernel(
    const float* __restrict__ x, const int* __restrict__ rp,
    unsigned short* __restrict__ Asw) {
  const int n = blockIdx.y, cb = blockIdx.x, tid = threadIdx.x;
  const int r = rp[n*4+0], c = rp[n*4+1], w = rp[n*4+2], h = rp[n*4+3];
  __shared__ float tile[8][24][25];
  __shared__ float pout[392];
  const int ch = tid >> 5, l32 = tid & 31;
  const float* xc = x + (((size_t)(n*C_CH + cb*8 + ch))*HF + c)*WF + r;
  for (int y = 0; y < h; ++y)
    for (int xx = l32; xx < w; xx += 32)
      tile[ch][y][xx] = xc[y*WF + xx];
  __syncthreads();
  for (int o = tid; o < 8*49; o += 256) {
    int ch2 = o / 49, ij = o - ch2*49, i = ij / 7, j = ij - i*7;
    int rs = (i*h)/7, re = ((i+1)*h + 6)/7;
    int cs = (j*w)/7, ce = ((j+1)*w + 6)/7;
    float m = -INFINITY;
    for (int y = rs; y < re; ++y)
      for (int xx = cs; xx < ce; ++xx)
        m = fmaxf(m, tile[ch2][y][xx]);
    pout[o] = m;
  }
  __syncthreads();
  if (tid < 49) {
    const int mt = n >> 4, mlo = n & 15;
    const int kl0 = tid * 8;
    const int kg0 = cb*392 + kl0;           // 8-aligned, one (S,kg) group
    const int S = kg0 >> 5, kg = (kg0 >> 3) & 3;
    size_t base = ((size_t)S*8 + mt)*512 + (size_t)(kg*16 + mlo)*8;
    unsigned short q[8];
    #pragma unroll
    for (int e = 0; e < 8; ++e) q[e] = bf_rne(pout[kl0 + e]);
    ushort4 lo; lo.x=q[0]; lo.y=q[1]; lo.z=q[2]; lo.w=q[3];
    ushort4 hi; hi.x=q[4]; hi.y=q[5]; hi.z=q[6]; hi.w=q[7];
    *(ushort4*)(Asw + base)     = lo;
    *(ushort4*)(Asw + base + 4) = hi;
  }
}

// ---------------------------------------------------------------------------
// Kernel 2: m97-style barrier'd split-K MFMA GEMM (round-17 structure, the
// session best) + XCD-AWARE SWIZZLE (T1): 1D grid of 512 blocks; hardware
// round-robins consecutive bids across the 8 XCDs, so decoding
//   xcd = bid&7, j = bid>>3, nb = j&31, ks = xcd*2 + (j>>5)
// pins each ks-PAIR of split-K slices to one XCD. Per-XCD A working set =
// 2 x 392KB = 784KB -> L2-resident -> A re-reads (200MB of the ~611MB
// fabric traffic that capped G1 at ~137us) become L2 hits.
// Arithmetic identical to rounds 14-20 (absmax must stay 2.0).
// ---------------------------------------------------------------------------
__global__ __launch_bounds__(256, 3) void gemm_v17(
    const unsigned short* __restrict__ Asw, const float* __restrict__ B,
    float* __restrict__ part, const int nsteps, const int swz) {
  __shared__ char smem[49152];          // [2][A:8KB | B:16KB]
  const int tid = threadIdx.x, lane = tid & 63, wv = tid >> 6;
  const int wr = wv >> 1, wc = wv & 1;
  const int bid = blockIdx.x;
  int nb, ks;
  if (swz) {
    const int xcd = bid & 7, j = bid >> 3;
    nb = j & 31;
    ks = xcd*2 + (j >> 5);
  } else {
    nb = bid & 31;
    ks = bid >> 5;
  }
  const int l15 = lane & 15, lq = lane >> 4;
  const float* Bg0 = B + (size_t)nb * 128;

  f32x4 acc[4][4];
  #pragma unroll
  for (int i = 0; i < 4; ++i)
    #pragma unroll
    for (int j2 = 0; j2 < 4; ++j2) acc[i][j2] = (f32x4){0.f, 0.f, 0.f, 0.f};

#define STAGE(s, bufb) do { \
    char* Ad = smem + (bufb); \
    char* Bd = smem + (bufb) + 8192; \
    _Pragma("unroll") \
    for (int t_ = 0; t_ < 6; ++t_) { \
      const int i_ = wv*6 + t_; \
      if (i_ < 8) { \
        gload16((const char*)Asw + (((size_t)(ks*nsteps + (s))*8 + i_) << 10) \
                    + lane*16, \
                Ad + (i_ << 10)); \
      } else { \
        const int j_ = i_ - 8; \
        const int row_ = 2*j_ + (lane >> 5); \
        const int gc_ = ((lane & 31)*4) ^ (8*((row_ >> 3) & 3)); \
        gload16(Bg0 + ((size_t)(ks*nsteps + (s))*32 + row_)*NH + gc_, \
                Bd + (j_ << 10)); \
      } \
    } } while (0)

  STAGE(0, 0);
  __syncthreads();

  int bufb = 0;
  for (int s = 0; s < nsteps; ++s) {
    if (s + 1 < nsteps) STAGE(s + 1, bufb ^ 24576);  // issue before compute
    const char* Ab = smem + bufb;
    const float* Bf = (const float*)(smem + bufb + 8192);
    s16x8 bf0[4];
    #pragma unroll
    for (int nt = 0; nt < 4; ++nt) {
      #pragma unroll
      for (int e = 0; e < 8; ++e) {
        float xv = Bf[(lq*8 + e)*128 + ((wc*64 + nt*16 + l15) ^ (8*lq))];
        bf0[nt][e] = (short)bf_rne(xv);
      }
    }
    #pragma unroll
    for (int ml = 0; ml < 4; ++ml) {
      const s16x8 a0 = *(const s16x8*)(Ab + ((wr*4 + ml) << 10) + lane*16);
      #pragma unroll
      for (int nt = 0; nt < 4; ++nt)
        acc[ml][nt] = __builtin_amdgcn_mfma_f32_16x16x32_bf16(
            a0, bf0[nt], acc[ml][nt], 0, 0, 0);
    }
    __syncthreads();
    bufb ^= 24576;
  }
#undef STAGE
  // epilogue: C/D layout row=(lane>>4)*4+rr, col=lane&15
  float* Pb = part + (size_t)ks*N_BATCH*NH + (size_t)nb*128 + wc*64;
  #pragma unroll
  for (int ml = 0; ml < 4; ++ml)
    #pragma unroll
    for (int nt = 0; nt < 4; ++nt)
      #pragma unroll
      for (int rr = 0; rr < 4; ++rr)
        Pb[(size_t)((wr*4 + ml)*16 + lq*4 + rr)*NH + nt*16 + l15]
            = acc[ml][nt][rr];
}

// ---------------------------------------------------------------------------
// Kernel 3: reduce split-K partials + bias + relu.
// mode 0: emit group-major 1-plane bf16 (A of next GEMM). mode 1: fp32 rows.
// ---------------------------------------------------------------------------
__global__ __launch_bounds__(256) void reduce_k(
    const float* __restrict__ part, const float* __restrict__ bias,
    unsigned short* __restrict__ AswOut, float* __restrict__ f32out,
    int KS, int mode) {
  const int idx = blockIdx.x*256 + threadIdx.x;     // float4 idx, 131072 total
  float4 s = ((const float4*)part)[idx];
  for (int k2 = 1; k2 < KS; ++k2) {
    float4 p = ((const float4*)part)[(size_t)k2*131072 + idx];
    s.x += p.x; s.y += p.y; s.z += p.z; s.w += p.w;
  }
  float4 bv = ((const float4*)bias)[idx & 1023];
  float v[4];
  v[0] = fmaxf(s.x + bv.x, 0.f); v[1] = fmaxf(s.y + bv.y, 0.f);
  v[2] = fmaxf(s.z + bv.z, 0.f); v[3] = fmaxf(s.w + bv.w, 0.f);
  if (mode == 1) {
    float4 o; o.x = v[0]; o.y = v[1]; o.z = v[2]; o.w = v[3];
    ((float4*)f32out)[idx] = o;
  } else {
    int m = idx >> 10, k = (idx & 1023) * 4;
    int S = k >> 5, kg = (k >> 3) & 3, e0 = k & 7;
    size_t base = ((size_t)S*8 + (m >> 4))*512
                + (size_t)(kg*16 + (m & 15))*8 + e0;
    ushort4 st;
    st.x = bf_rne(v[0]); st.y = bf_rne(v[1]);
    st.z = bf_rne(v[2]); st.w = bf_rne(v[3]);
    *(ushort4*)(AswOut + base) = st;
  }
}

// ---------------------------------------------------------------------------
// Kernel 4a: transpose Wcls|Wbox into WT[101][4096]
// ---------------------------------------------------------------------------
__global__ __launch_bounds__(256) void head_transpose(
    const float* __restrict__ Wcls, const float* __restrict__ Wbox,
    float* __restrict__ WT) {
  const int c = blockIdx.x;
  const float* src; int stride;
  if (c < NCLS) { src = Wcls + c; stride = NCLS; }
  else          { src = Wbox + (c - NCLS); stride = NBOX; }
  for (int k = threadIdx.x; k < NH; k += 256)
    WT[(size_t)c*NH + k] = src[(size_t)k*stride];
}

// ---------------------------------------------------------------------------
// Kernel 4b: fused head — dots (8 waves x stride-8 cols, h2 row in LDS)
// + softmax(21) + bbox(80).
// ---------------------------------------------------------------------------
__global__ __launch_bounds__(512) void head_fused(
    const float* __restrict__ h2, const float* __restrict__ WT,
    const int* __restrict__ rp, float* __restrict__ out) {
  const int n = blockIdx.x, tid = threadIdx.x;
  const int wv = tid >> 6, lane = tid & 63;
  __shared__ float h2s[NH];
  __shared__ float dots[104];
  __shared__ float red[2];
  for (int i = tid; i < NH/4; i += 512)
    ((float4*)h2s)[i] = ((const float4*)(h2 + (size_t)n*NH))[i];
  __syncthreads();
  for (int c = wv; c < NCLS + NBOX; c += 8) {
    const float4* hp = (const float4*)h2s;
    const float4* wp = (const float4*)(WT + (size_t)c*NH);
    float s0=0.f, s1=0.f, s2=0.f, s3=0.f;
    #pragma unroll
    for (int it = 0; it < 16; ++it) {
      float4 a = hp[it*64 + lane];
      float4 b = wp[it*64 + lane];
      s0 = fmaf(a.x, b.x, s0); s1 = fmaf(a.y, b.y, s1);
      s2 = fmaf(a.z, b.z, s2); s3 = fmaf(a.w, b.w, s3);
    }
    float v = (s0 + s1) + (s2 + s3);
    #pragma unroll
    for (int m = 32; m >= 1; m >>= 1) v += __shfl_xor(v, m, 64);
    if (lane == 0) dots[c] = v;
  }
  __syncthreads();
  if (tid == 0) {
    float m = dots[0];
    for (int i = 1; i < NCLS; ++i) m = fmaxf(m, dots[i]);
    float s = 0.f;
    for (int i = 0; i < NCLS; ++i) s += expf(dots[i] - m);
    red[0] = m; red[1] = s;
  }
  __syncthreads();
  if (tid < NCLS) {
    out[(size_t)n*NCLS + tid] = expf(dots[tid] - red[0]) / red[1];
  } else if (tid < NCLS + NBOX) {
    const int j = tid - NCLS;
    const float t  = dots[tid];
    const float rf = (float)rp[n*4+0];
    const float cf = (float)rp[n*4+1];
    const float wf = (float)rp[n*4+2];
    const float hf = (float)rp[n*4+3];
    float p;
    switch (j & 3) {
      case 0:  p = ceilf (__fmul_rn(__fadd_rn(__fmul_rn(wf, t), rf), 16.f)) - 1.f; break;
      case 1:  p = ceilf (__fmul_rn(__fadd_rn(__fmul_rn(hf, t), cf), 16.f)) - 1.f; break;
      case 2:  p = floorf(__fmul_rn(__fmul_rn(wf, expf(t)), 16.f)) + 1.f; break;
      default: p = floorf(__fmul_rn(__fmul_rn(hf, expf(t)), 16.f)) + 1.f; break;
    }
    out[(size_t)N_BATCH*NCLS + (size_t)n*NBOX + j] = p;
  }
}

// ---------------------------------------------------------------------------
extern "C" void kernel_launch(void* const* d_in, const int* in_sizes, int n_in,
                              void* d_out, int out_size, void* d_ws, size_t ws_size,
                              hipStream_t stream) {
  const float* x    = (const float*)d_in[0];
  const int*   rp   = (const int*)  d_in[1];
  const float* W1   = (const float*)d_in[2];
  const float* b1   = (const float*)d_in[3];
  const float* W2   = (const float*)d_in[4];
  const float* b2   = (const float*)d_in[5];
  const float* Wcls = (const float*)d_in[6];
  const float* Wbox = (const float*)d_in[7];
  float* out = (float*)d_out;

  // ws: Asw1 (6.4MB) | Asw2 (1.05MB) | h2f | WT | part (~42 MB total)
  char* wp = (char*)d_ws;
  unsigned short* Asw1 = (unsigned short*)wp; wp += (size_t)STEPS1*8192;
  unsigned short* Asw2 = (unsigned short*)wp; wp += (size_t)STEPS2*8192;
  float* h2f = (float*)wp;            wp += (size_t)N_BATCH*NH*4;
  float* WT  = (float*)wp;            wp += (size_t)(NCLS+NBOX)*NH*4;
  float* part = (float*)wp;
  const size_t fixed = (size_t)(wp - (char*)d_ws);
  const size_t slab = (size_t)N_BATCH*NH*4;       // 2 MB per partial
  const int KS = 16;                               // swizzle assumes 16
  const int swz = (fixed + 16*slab <= ws_size) ? 1 : 1;  // ws is ~1.6GB

  pool_kernel<<<dim3(64, 128), 256, 0, stream>>>(x, rp, Asw1);
  head_transpose<<<dim3(NCLS + NBOX), 256, 0, stream>>>(Wcls, Wbox, WT);

  // GEMM1: 1D grid 512, XCD-swizzled (ks-pair per XCD), nsteps=49.
  gemm_v17<<<dim3(512), 256, 0, stream>>>(Asw1, W1, part, STEPS1/KS, swz);
  reduce_k<<<dim3(512), 256, 0, stream>>>(part, b1, Asw2, nullptr, KS, 0);

  // GEMM2: 1D grid 512, XCD-swizzled, nsteps=8.
  gemm_v17<<<dim3(512), 256, 0, stream>>>(Asw2, W2, part, STEPS2/KS, swz);
  reduce_k<<<dim3(512), 256, 0, stream>>>(part, b2, nullptr, h2f, KS, 1);

  head_fused<<<dim3(128), 512, 0, stream>>>(h2f, WT, rp, out);
}